// Round 1
// baseline (793.712 us; speedup 1.0000x reference)
//
#include <hip/hip_runtime.h>
#include <cstddef>

#define LEN_T 11253
#define TOK   22506     // BS * LEN
#define NHEADS 8
#define DH_    32
#define DMODEL 256
#define DFF_   1024

// ---------------- top-k over 7x7 mask window ----------------
// one thread per (b, q, h); writes offsets (pixel units) + softmax4/4 weights
__global__ __launch_bounds__(256) void topk_kernel(
    const float* __restrict__ m0, const float* __restrict__ m1,
    const float* __restrict__ m2, const float* __restrict__ m3,
    const float* __restrict__ pm_w, const float* __restrict__ pm_b,
    float* __restrict__ offs, float* __restrict__ attw)
{
  int t = blockIdx.x * 256 + threadIdx.x;
  if (t >= TOK * NHEADS) return;
  int h  = t & 7;
  int bq = t >> 3;
  int b  = bq / LEN_T;
  int q  = bq - b * LEN_T;
  int l, st, H_, W_;
  const float* mk;
  if (q < 8464)       { l = 0; st = 0;     H_ = 92; W_ = 92; mk = m0; }
  else if (q < 10580) { l = 1; st = 8464;  H_ = 46; W_ = 46; mk = m1; }
  else if (q < 11109) { l = 2; st = 10580; H_ = 23; W_ = 23; mk = m2; }
  else                { l = 3; st = 11109; H_ = 12; W_ = 12; mk = m3; }
  int pos = q - st;
  int rr = pos / W_;
  int cc = pos - rr * W_;
  float w  = pm_w[l * NHEADS + h];
  float bb = pm_b[l * NHEADS + h];
  const float* mp = mk + (size_t)b * H_ * W_;

  // stable top-4 (descending, ties -> lower k) == jax.lax.top_k semantics
  float bestv[4] = {-1e30f, -1e30f, -1e30f, -1e30f};
  int   bestk[4] = {0, 0, 0, 0};
  for (int k = 0; k < 49; ++k) {
    int i = k / 7, j = k - (k / 7) * 7;
    int yy = rr + i - 3, xx = cc + j - 3;
    float v = 0.f;                       // zero padding outside the map
    if (yy >= 0 && yy < H_ && xx >= 0 && xx < W_) v = mp[yy * W_ + xx] * w + bb;
    if (v > bestv[3]) {                  // strict >: earlier k wins ties
      int p4 = 3;
      while (p4 > 0 && v > bestv[p4 - 1]) {
        bestv[p4] = bestv[p4 - 1]; bestk[p4] = bestk[p4 - 1]; --p4;
      }
      bestv[p4] = v; bestk[p4] = k;
    }
  }
  // softmax over 16 = 4 values repeated 4x  ->  exp(v_p)/(4*sum_p exp)
  float mx = bestv[0];
  float ee[4];
  float s = 0.f;
  #pragma unroll
  for (int p = 0; p < 4; ++p) { ee[p] = expf(bestv[p] - mx); s += ee[p]; }
  float inv = 1.f / (4.f * s);
  float* op = offs + (size_t)t * 8;
  float* wp = attw + (size_t)t * 4;
  #pragma unroll
  for (int p = 0; p < 4; ++p) {
    int k = bestk[p];
    int i = k / 7, j = k - i * 7;
    op[2 * p]     = (float)(j - 3);   // x offset (pixels)
    op[2 * p + 1] = (float)(i - 3);   // y offset
    wp[p] = ee[p] * inv;
  }
}

// ---------------- deformable bilinear sampling ----------------
// one block per (b,q): 8 heads x 32 dh lanes. Coalesced 32-float gathers.
__global__ __launch_bounds__(256) void sample_kernel(
    const float* __restrict__ V, const float* __restrict__ refpts,
    const float* __restrict__ offs, const float* __restrict__ attw,
    float* __restrict__ outp)
{
  int blk = blockIdx.x;            // b*LEN + q
  int b   = blk / LEN_T;
  int h   = threadIdx.x >> 5;
  int dh  = threadIdx.x & 31;
  const float* op = offs + (size_t)blk * 64 + h * 8;
  const float* wp = attw + (size_t)blk * 32 + h * 4;
  float ox[4], oy[4], w4[4];
  #pragma unroll
  for (int p = 0; p < 4; ++p) { ox[p] = op[2*p]; oy[p] = op[2*p+1]; w4[p] = wp[p]; }
  const float* rp = refpts + (size_t)blk * 8;   // (NL,2)
  const int Hs[4] = {92, 46, 23, 12};
  const int Ss[4] = {0, 8464, 10580, 11109};
  float acc = 0.f;
  #pragma unroll
  for (int l = 0; l < 4; ++l) {
    int H_ = Hs[l], W_ = Hs[l], st = Ss[l];
    // loc*W - 0.5 = ref*W + off - 0.5 (offsets already in pixels of every level)
    float rx = rp[2*l]     * (float)W_ - 0.5f;
    float ry = rp[2*l + 1] * (float)H_ - 0.5f;
    const float* vb = V + ((size_t)(b * LEN_T + st)) * DMODEL + h * DH_ + dh;
    #pragma unroll
    for (int p = 0; p < 4; ++p) {
      float xx = rx + ox[p], yy = ry + oy[p];
      float x0f = floorf(xx), y0f = floorf(yy);
      float tx = xx - x0f, ty = yy - y0f;
      int x0 = (int)x0f, y0 = (int)y0f;
      float s = 0.f;
      #pragma unroll
      for (int cy = 0; cy < 2; ++cy) {
        #pragma unroll
        for (int cx = 0; cx < 2; ++cx) {
          int yi = y0 + cy, xi = x0 + cx;
          float wgt = (cx ? tx : 1.f - tx) * (cy ? ty : 1.f - ty);
          bool valid = (xi >= 0) && (xi < W_) && (yi >= 0) && (yi < H_);
          int yc = min(max(yi, 0), H_ - 1);
          int xc = min(max(xi, 0), W_ - 1);
          float v = vb[(size_t)(yc * W_ + xc) * DMODEL];
          s += valid ? v * wgt : 0.f;
        }
      }
      acc += w4[p] * s;
    }
  }
  outp[(size_t)blk * DMODEL + threadIdx.x] = acc;
}

// ---------------- fused f32 GEMM: C = A@B + bias [+res, LN] ----------------
// block tile: 32 rows x 256 cols; 256 threads = 4 waves; wave ty owns rows
// ty*8..ty*8+7 and all 256 cols -> LN reduces within one wave via shfl_xor.
// EPI: 0 = bias, 1 = bias+relu, 2 = bias + residual + LayerNorm (N must be 256)
template<int EPI>
__global__ __launch_bounds__(256) void gemm_kernel(
    const float* __restrict__ A, const float* __restrict__ B,
    const float* __restrict__ bias, const float* __restrict__ res,
    const float* __restrict__ lng, const float* __restrict__ lnb,
    float* __restrict__ C, int M, int K, int N)
{
  __shared__ float As[32][36];   // [k][m], stride 36 keeps float4 alignment
  __shared__ float Bs[32][256];  // [k][n]
  const int tid = threadIdx.x;
  const int ty = tid >> 6;       // wave id 0..3
  const int tx = tid & 63;       // lane
  const int row0 = blockIdx.x * 32;
  const int col0 = blockIdx.y * 256;
  float acc[8][4];
  #pragma unroll
  for (int i = 0; i < 8; ++i)
    #pragma unroll
    for (int j = 0; j < 4; ++j) acc[i][j] = 0.f;

  for (int kb = 0; kb < K; kb += 32) {
    { // A tile 32x32, transposed into LDS
      int lin = tid * 4;
      int r = lin >> 5;
      int c = lin & 31;
      int gr = row0 + r; if (gr >= M) gr = M - 1;
      float4 av = *(const float4*)(A + (size_t)gr * K + kb + c);
      As[c + 0][r] = av.x; As[c + 1][r] = av.y;
      As[c + 2][r] = av.z; As[c + 3][r] = av.w;
    }
    { // B tile 32x256
      const float* Bp = B + (size_t)kb * N + col0;
      #pragma unroll
      for (int c8 = 0; c8 < 8; ++c8) {
        int lin = c8 * 1024 + tid * 4;
        int r = lin >> 8;
        int c = lin & 255;
        *(float4*)&Bs[r][c] = *(const float4*)(Bp + (size_t)r * N + c);
      }
    }
    __syncthreads();
    #pragma unroll
    for (int k = 0; k < 32; ++k) {
      float4 a0 = *(const float4*)&As[k][ty * 8];
      float4 a1 = *(const float4*)&As[k][ty * 8 + 4];
      float4 b4 = *(const float4*)&Bs[k][tx * 4];
      float av[8] = {a0.x, a0.y, a0.z, a0.w, a1.x, a1.y, a1.z, a1.w};
      float bv[4] = {b4.x, b4.y, b4.z, b4.w};
      #pragma unroll
      for (int i = 0; i < 8; ++i)
        #pragma unroll
        for (int j = 0; j < 4; ++j) acc[i][j] += av[i] * bv[j];
    }
    __syncthreads();
  }

  const int c = col0 + tx * 4;
  const float4 bias4 = *(const float4*)(bias + c);
  if constexpr (EPI == 2) {
    const float4 g4  = *(const float4*)(lng + c);
    const float4 be4 = *(const float4*)(lnb + c);
    float vals[8][4], s[8], sq[8];
    #pragma unroll
    for (int i = 0; i < 8; ++i) {
      int gr = row0 + ty * 8 + i;
      int grc = gr < M ? gr : M - 1;
      float4 r4 = *(const float4*)(res + (size_t)grc * 256 + c);
      vals[i][0] = acc[i][0] + bias4.x + r4.x;
      vals[i][1] = acc[i][1] + bias4.y + r4.y;
      vals[i][2] = acc[i][2] + bias4.z + r4.z;
      vals[i][3] = acc[i][3] + bias4.w + r4.w;
      s[i]  = vals[i][0] + vals[i][1] + vals[i][2] + vals[i][3];
      sq[i] = vals[i][0]*vals[i][0] + vals[i][1]*vals[i][1]
            + vals[i][2]*vals[i][2] + vals[i][3]*vals[i][3];
    }
    #pragma unroll
    for (int off = 1; off < 64; off <<= 1) {
      #pragma unroll
      for (int i = 0; i < 8; ++i) {
        s[i]  += __shfl_xor(s[i],  off, 64);
        sq[i] += __shfl_xor(sq[i], off, 64);
      }
    }
    #pragma unroll
    for (int i = 0; i < 8; ++i) {
      int gr = row0 + ty * 8 + i;
      if (gr < M) {
        float mu  = s[i]  * (1.f / 256.f);
        float var = sq[i] * (1.f / 256.f) - mu * mu;   // biased var (jnp.var)
        float rs  = rsqrtf(var + 1e-5f);
        float4 o;
        o.x = (vals[i][0] - mu) * rs * g4.x + be4.x;
        o.y = (vals[i][1] - mu) * rs * g4.y + be4.y;
        o.z = (vals[i][2] - mu) * rs * g4.z + be4.z;
        o.w = (vals[i][3] - mu) * rs * g4.w + be4.w;
        *(float4*)(C + (size_t)gr * 256 + c) = o;
      }
    }
  } else {
    #pragma unroll
    for (int i = 0; i < 8; ++i) {
      int gr = row0 + ty * 8 + i;
      if (gr < M) {
        float4 o;
        o.x = acc[i][0] + bias4.x;
        o.y = acc[i][1] + bias4.y;
        o.z = acc[i][2] + bias4.z;
        o.w = acc[i][3] + bias4.w;
        if constexpr (EPI == 1) {
          o.x = fmaxf(o.x, 0.f); o.y = fmaxf(o.y, 0.f);
          o.z = fmaxf(o.z, 0.f); o.w = fmaxf(o.w, 0.f);
        }
        *(float4*)(C + (size_t)gr * N + c) = o;
      }
    }
  }
}

extern "C" void kernel_launch(void* const* d_in, const int* in_sizes, int n_in,
                              void* d_out, int out_size, void* d_ws, size_t ws_size,
                              hipStream_t stream)
{
  const float* src    = (const float*)d_in[0];
  // d_in[1] = pos (unused by reference), d_in[3] = window_grid (hardcoded),
  // d_in[8] = spatial_shapes, d_in[9] = level_start_index (hardcoded)
  const float* refpts = (const float*)d_in[2];
  const float* m0   = (const float*)d_in[4];
  const float* m1   = (const float*)d_in[5];
  const float* m2   = (const float*)d_in[6];
  const float* m3   = (const float*)d_in[7];
  const float* pm_w = (const float*)d_in[10];
  const float* pm_b = (const float*)d_in[11];
  const float* Wv   = (const float*)d_in[12];
  const float* bv   = (const float*)d_in[13];
  const float* Wo   = (const float*)d_in[14];
  const float* bo   = (const float*)d_in[15];
  const float* ln1g = (const float*)d_in[16];
  const float* ln1b = (const float*)d_in[17];
  const float* W1   = (const float*)d_in[18];
  const float* b1   = (const float*)d_in[19];
  const float* W2   = (const float*)d_in[20];
  const float* b2   = (const float*)d_in[21];
  const float* ln2g = (const float*)d_in[22];
  const float* ln2b = (const float*)d_in[23];
  float* out = (float*)d_out;
  float* ws  = (float*)d_ws;

  const size_t sz_tok = (size_t)TOK * DMODEL;     // 5,761,536 floats
  float* V       = ws;
  float* attnpre = ws + sz_tok;
  float* x       = ws + 2 * sz_tok;
  float* offs    = ws + 3 * sz_tok;               // TOK*64 floats
  float* attw    = offs + (size_t)TOK * 64;       // TOK*32 floats
  // FFN hidden (11253 x 1024 = exactly 2*sz_tok) aliases V+attnpre, which are
  // dead once x has been produced. Total ws use ~74 MiB.
  float* h1      = ws;

  topk_kernel<<<dim3((TOK * NHEADS + 255) / 256), 256, 0, stream>>>(
      m0, m1, m2, m3, pm_w, pm_b, offs, attw);

  // V = src @ Wv + bv
  gemm_kernel<0><<<dim3((TOK + 31) / 32, 1), 256, 0, stream>>>(
      src, Wv, bv, nullptr, nullptr, nullptr, V, TOK, 256, 256);

  // deformable attention -> attnpre
  sample_kernel<<<dim3(TOK), 256, 0, stream>>>(V, refpts, offs, attw, attnpre);

  // x = LN1(src + attnpre @ Wo + bo)
  gemm_kernel<2><<<dim3((TOK + 31) / 32, 1), 256, 0, stream>>>(
      attnpre, Wo, bo, src, ln1g, ln1b, x, TOK, 256, 256);

  // FFN per batch element (hidden buffer reuse keeps workspace small)
  for (int ch = 0; ch < 2; ++ch) {
    const float* xc = x   + (size_t)ch * LEN_T * DMODEL;
    float*       oc = out + (size_t)ch * LEN_T * DMODEL;
    gemm_kernel<1><<<dim3((LEN_T + 31) / 32, 4), 256, 0, stream>>>(
        xc, W1, b1, nullptr, nullptr, nullptr, h1, LEN_T, 256, 1024);
    gemm_kernel<2><<<dim3((LEN_T + 31) / 32, 1), 256, 0, stream>>>(
        h1, W2, b2, xc, ln2g, ln2b, oc, LEN_T, 1024, 256);
  }
}

// Round 2
// 450.949 us; speedup vs baseline: 1.7601x; 1.7601x over previous
//
#include <hip/hip_runtime.h>
#include <cstddef>
#include <cstdint>

#define LEN_T 11253
#define TOK   22506     // BS * LEN
#define NHEADS 8
#define DMODEL 256

typedef __attribute__((ext_vector_type(8))) short short8;   // bf16x8 (4 VGPR)
typedef __attribute__((ext_vector_type(4))) float f32x4;

__device__ __forceinline__ unsigned short f2bf(float f) {
  union { float f; unsigned u; } v; v.f = f;
  unsigned r = v.u + 0x7fffu + ((v.u >> 16) & 1u);   // RNE
  return (unsigned short)(r >> 16);
}

__device__ __forceinline__ void gld_lds16(const void* g, void* l) {
  __builtin_amdgcn_global_load_lds(
      (const __attribute__((address_space(1))) void*)g,
      (__attribute__((address_space(3))) void*)l, 16, 0, 0);
}

// ---------------- cast src f32 -> bf16 ----------------
__global__ __launch_bounds__(256) void cast_src_kernel(
    const float* __restrict__ in, unsigned short* __restrict__ out, int n4)
{
  int i = blockIdx.x * 256 + threadIdx.x;
  if (i < n4) {
    float4 v = ((const float4*)in)[i];
    uint2 o;
    o.x = (unsigned)f2bf(v.x) | ((unsigned)f2bf(v.y) << 16);
    o.y = (unsigned)f2bf(v.z) | ((unsigned)f2bf(v.w) << 16);
    ((uint2*)out)[i] = o;
  }
}

// ---------------- cast + transpose weight: W (K x N) -> Bt (N x K) bf16 ----
__global__ __launch_bounds__(256) void castT_kernel(
    const float* __restrict__ W, unsigned short* __restrict__ Bt, int lk, int ln)
{
  int i = blockIdx.x * 256 + threadIdx.x;
  int total = 1 << (lk + ln);
  if (i < total) {
    int n = i >> lk;
    int k = i & ((1 << lk) - 1);
    Bt[i] = f2bf(W[((size_t)k << ln) + n]);
  }
}

// ---------------- top-k over 7x7 mask window ----------------
__global__ __launch_bounds__(256) void topk_kernel(
    const float* __restrict__ m0, const float* __restrict__ m1,
    const float* __restrict__ m2, const float* __restrict__ m3,
    const float* __restrict__ pm_w, const float* __restrict__ pm_b,
    float* __restrict__ offs, float* __restrict__ attw)
{
  int t = blockIdx.x * 256 + threadIdx.x;
  if (t >= TOK * NHEADS) return;
  int h  = t & 7;
  int bq = t >> 3;
  int b  = bq / LEN_T;
  int q  = bq - b * LEN_T;
  int l, st, H_, W_;
  const float* mk;
  if (q < 8464)       { l = 0; st = 0;     H_ = 92; W_ = 92; mk = m0; }
  else if (q < 10580) { l = 1; st = 8464;  H_ = 46; W_ = 46; mk = m1; }
  else if (q < 11109) { l = 2; st = 10580; H_ = 23; W_ = 23; mk = m2; }
  else                { l = 3; st = 11109; H_ = 12; W_ = 12; mk = m3; }
  int pos = q - st;
  int rr = pos / W_;
  int cc = pos - rr * W_;
  float w  = pm_w[l * NHEADS + h];
  float bb = pm_b[l * NHEADS + h];
  const float* mp = mk + (size_t)b * H_ * W_;

  float bestv[4] = {-1e30f, -1e30f, -1e30f, -1e30f};
  int   bestk[4] = {0, 0, 0, 0};
  for (int k = 0; k < 49; ++k) {
    int i = k / 7, j = k - (k / 7) * 7;
    int yy = rr + i - 3, xx = cc + j - 3;
    float v = 0.f;                       // zero padding outside the map
    if (yy >= 0 && yy < H_ && xx >= 0 && xx < W_) v = mp[yy * W_ + xx] * w + bb;
    if (v > bestv[3]) {                  // strict >: earlier k wins ties
      int p4 = 3;
      while (p4 > 0 && v > bestv[p4 - 1]) {
        bestv[p4] = bestv[p4 - 1]; bestk[p4] = bestk[p4 - 1]; --p4;
      }
      bestv[p4] = v; bestk[p4] = k;
    }
  }
  float mx = bestv[0];
  float ee[4];
  float s = 0.f;
  #pragma unroll
  for (int p = 0; p < 4; ++p) { ee[p] = __expf(bestv[p] - mx); s += ee[p]; }
  float inv = 1.f / (4.f * s);
  float* op = offs + (size_t)t * 8;
  float* wp = attw + (size_t)t * 4;
  #pragma unroll
  for (int p = 0; p < 4; ++p) {
    int k = bestk[p];
    int i = k / 7, j = k - i * 7;
    op[2 * p]     = (float)(j - 3);   // x offset (pixels)
    op[2 * p + 1] = (float)(i - 3);   // y offset
    wp[p] = ee[p] * inv;
  }
}

// ---------------- deformable bilinear sampling ----------------
// one wave per token. Phase 1: 64 lanes compute 128 (h,l,p) tuples -> LDS.
// Phase 2: lane = h*8+dg handles head h, dh = dg*4..dg*4+3 (float4 gathers).
__global__ __launch_bounds__(256) void sample_kernel(
    const float* __restrict__ V, const float* __restrict__ refpts,
    const float* __restrict__ offs, const float* __restrict__ attw,
    unsigned short* __restrict__ outp)
{
  __shared__ int4  sidx[4][128];
  __shared__ float4 swgt[4][128];
  const int wv   = threadIdx.x >> 6;
  const int lane = threadIdx.x & 63;
  const int blk  = blockIdx.x * 4 + wv;      // b*LEN + q
  const bool ok  = blk < TOK;

  if (ok) {
    const int b = (blk >= LEN_T) ? 1 : 0;
    const float* rp = refpts + (size_t)blk * 8;
    #pragma unroll
    for (int e = 0; e < 2; ++e) {
      int t = lane * 2 + e;                  // t = lp*8 + h
      int h = t & 7, lp = t >> 3;
      int l = lp >> 2, p = lp & 3;
      float ox = offs[((size_t)blk * 8 + h) * 8 + p * 2];
      float oy = offs[((size_t)blk * 8 + h) * 8 + p * 2 + 1];
      float aw = attw[((size_t)blk * 8 + h) * 4 + p];
      int H_ = (l == 0) ? 92 : (l == 1) ? 46 : (l == 2) ? 23 : 12;  // square levels
      int st = (l == 0) ? 0  : (l == 1) ? 8464 : (l == 2) ? 10580 : 11109;
      float xx = rp[2 * l]     * (float)H_ - 0.5f + ox;
      float yy = rp[2 * l + 1] * (float)H_ - 0.5f + oy;
      float x0f = floorf(xx), y0f = floorf(yy);
      float tx = xx - x0f, ty = yy - y0f;
      int x0 = (int)x0f, y0 = (int)y0f;
      int base = b * LEN_T + st;
      float wc0 = (1.f - tx) * (1.f - ty);
      float wc1 = tx * (1.f - ty);
      float wc2 = (1.f - tx) * ty;
      float wc3 = tx * ty;
      int4 idx; float4 wg;
      {
        int xi = x0, yi = y0;
        bool v_ = (xi >= 0) & (xi < H_) & (yi >= 0) & (yi < H_);
        idx.x = base + min(max(yi, 0), H_ - 1) * H_ + min(max(xi, 0), H_ - 1);
        wg.x = v_ ? aw * wc0 : 0.f;
      }
      {
        int xi = x0 + 1, yi = y0;
        bool v_ = (xi >= 0) & (xi < H_) & (yi >= 0) & (yi < H_);
        idx.y = base + min(max(yi, 0), H_ - 1) * H_ + min(max(xi, 0), H_ - 1);
        wg.y = v_ ? aw * wc1 : 0.f;
      }
      {
        int xi = x0, yi = y0 + 1;
        bool v_ = (xi >= 0) & (xi < H_) & (yi >= 0) & (yi < H_);
        idx.z = base + min(max(yi, 0), H_ - 1) * H_ + min(max(xi, 0), H_ - 1);
        wg.z = v_ ? aw * wc2 : 0.f;
      }
      {
        int xi = x0 + 1, yi = y0 + 1;
        bool v_ = (xi >= 0) & (xi < H_) & (yi >= 0) & (yi < H_);
        idx.w = base + min(max(yi, 0), H_ - 1) * H_ + min(max(xi, 0), H_ - 1);
        wg.w = v_ ? aw * wc3 : 0.f;
      }
      sidx[wv][t] = idx;
      swgt[wv][t] = wg;
    }
  }
  __syncthreads();

  if (ok) {
    const int h = lane >> 3, dg = lane & 7;
    const float* vb = V + h * 32 + dg * 4;
    f32x4 acc = {0.f, 0.f, 0.f, 0.f};
    #pragma unroll 4
    for (int lp = 0; lp < 16; ++lp) {
      int4  idx = sidx[wv][lp * 8 + h];
      float4 wg = swgt[wv][lp * 8 + h];
      float4 v0 = *(const float4*)(vb + (size_t)idx.x * DMODEL);
      float4 v1 = *(const float4*)(vb + (size_t)idx.y * DMODEL);
      float4 v2 = *(const float4*)(vb + (size_t)idx.z * DMODEL);
      float4 v3 = *(const float4*)(vb + (size_t)idx.w * DMODEL);
      acc.x += wg.x * v0.x + wg.y * v1.x + wg.z * v2.x + wg.w * v3.x;
      acc.y += wg.x * v0.y + wg.y * v1.y + wg.z * v2.y + wg.w * v3.y;
      acc.z += wg.x * v0.z + wg.y * v1.z + wg.z * v2.z + wg.w * v3.z;
      acc.w += wg.x * v0.w + wg.y * v1.w + wg.z * v2.w + wg.w * v3.w;
    }
    uint2 o;
    o.x = (unsigned)f2bf(acc.x) | ((unsigned)f2bf(acc.y) << 16);
    o.y = (unsigned)f2bf(acc.z) | ((unsigned)f2bf(acc.w) << 16);
    *(uint2*)(outp + (size_t)blk * DMODEL + h * 32 + dg * 4) = o;
  }
}

// ---------------- bf16 MFMA GEMM (m97 structure) ----------------
// C[M,N] = A[M,K](bf16) @ Bt[N,K](bf16)^T + bias [+res]
// block 128x128, BK=32, 4 waves in 2x2, wave tile 64x64 (4x4 of 16x16x32).
// EPI: 0 = bias -> f32 C; 1 = bias+relu -> bf16 Cb; 2 = bias+res -> f32 C
template<int EPI>
__global__ __launch_bounds__(256) void mfma_gemm(
    const short* __restrict__ A, const short* __restrict__ Bt,
    const float* __restrict__ bias, const float* __restrict__ res,
    float* __restrict__ C, unsigned short* __restrict__ Cb,
    int M, int N, int K)
{
  __shared__ short As[128 * 32] __attribute__((aligned(16)));
  __shared__ short Bs[128 * 32] __attribute__((aligned(16)));
  const int tid  = threadIdx.x;
  const int w    = tid >> 6;
  const int lane = tid & 63;
  const int row0 = blockIdx.x * 128;
  const int col0 = blockIdx.y * 128;

  f32x4 acc[4][4];
  #pragma unroll
  for (int i = 0; i < 4; ++i)
    #pragma unroll
    for (int j = 0; j < 4; ++j) acc[i][j] = (f32x4){0.f, 0.f, 0.f, 0.f};

  // staging: 8 chunks of 16 rows; wave w stages chunks 2w, 2w+1.
  // lane t within chunk: row = t>>2 (64B rows), k-quarter = t&3 (16B)
  const int c0 = w * 2, c1 = w * 2 + 1;
  const int rA0 = min(row0 + c0 * 16 + (lane >> 2), M - 1);
  const int rA1 = min(row0 + c1 * 16 + (lane >> 2), M - 1);
  const int rB0 = col0 + c0 * 16 + (lane >> 2);     // N multiple of 128
  const int rB1 = col0 + c1 * 16 + (lane >> 2);
  const short* a0p = A + (size_t)rA0 * K + (lane & 3) * 8;
  const short* a1p = A + (size_t)rA1 * K + (lane & 3) * 8;
  const short* b0p = Bt + (size_t)rB0 * K + (lane & 3) * 8;
  const short* b1p = Bt + (size_t)rB1 * K + (lane & 3) * 8;
  short* lA0 = As + c0 * 512 + lane * 8;
  short* lA1 = As + c1 * 512 + lane * 8;
  short* lB0 = Bs + c0 * 512 + lane * 8;
  short* lB1 = Bs + c1 * 512 + lane * 8;

  const int wm = (w & 1) * 64, wn = (w >> 1) * 64;
  const short* Abase = As + (size_t)(wm + (lane & 15)) * 32 + (lane >> 4) * 8;
  const short* Bbase = Bs + (size_t)(wn + (lane & 15)) * 32 + (lane >> 4) * 8;

  for (int kb = 0; kb < K; kb += 32) {
    gld_lds16(a0p + kb, lA0);
    gld_lds16(a1p + kb, lA1);
    gld_lds16(b0p + kb, lB0);
    gld_lds16(b1p + kb, lB1);
    __syncthreads();
    short8 af[4], bfr[4];
    #pragma unroll
    for (int mt = 0; mt < 4; ++mt) af[mt]  = *(const short8*)(Abase + mt * 16 * 32);
    #pragma unroll
    for (int nt = 0; nt < 4; ++nt) bfr[nt] = *(const short8*)(Bbase + nt * 16 * 32);
    #pragma unroll
    for (int mt = 0; mt < 4; ++mt)
      #pragma unroll
      for (int nt = 0; nt < 4; ++nt)
        acc[mt][nt] = __builtin_amdgcn_mfma_f32_16x16x32_bf16(
            af[mt], bfr[nt], acc[mt][nt], 0, 0, 0);
    __syncthreads();
  }

  // epilogue: C/D layout col=lane&15, row=(lane>>4)*4+reg
  const int colq = lane & 15, quad = lane >> 4;
  #pragma unroll
  for (int nt = 0; nt < 4; ++nt) {
    const int col = col0 + wn + nt * 16 + colq;
    const float bv_ = bias[col];
    #pragma unroll
    for (int mt = 0; mt < 4; ++mt) {
      #pragma unroll
      for (int r = 0; r < 4; ++r) {
        int row = row0 + wm + mt * 16 + quad * 4 + r;
        if (row < M) {
          float f = acc[mt][nt][r] + bv_;
          if constexpr (EPI == 1) {
            Cb[(size_t)row * N + col] = f2bf(fmaxf(f, 0.f));
          } else {
            if constexpr (EPI == 2) f += res[(size_t)row * N + col];
            C[(size_t)row * N + col] = f;
          }
        }
      }
    }
  }
}

// ---------------- LayerNorm: one wave per row (256 cols) ----------------
template<bool WBF>
__global__ __launch_bounds__(256) void ln_kernel(
    const float* __restrict__ in, const float* __restrict__ g,
    const float* __restrict__ be, float* __restrict__ outf,
    unsigned short* __restrict__ outb, int M)
{
  int row  = blockIdx.x * 4 + (threadIdx.x >> 6);
  int lane = threadIdx.x & 63;
  if (row >= M) return;
  float4 v = *(const float4*)(in + (size_t)row * 256 + lane * 4);
  float s  = v.x + v.y + v.z + v.w;
  float sq = v.x * v.x + v.y * v.y + v.z * v.z + v.w * v.w;
  #pragma unroll
  for (int off = 1; off < 64; off <<= 1) {
    s  += __shfl_xor(s,  off, 64);
    sq += __shfl_xor(sq, off, 64);
  }
  float mu  = s * (1.f / 256.f);
  float var = sq * (1.f / 256.f) - mu * mu;   // biased var (jnp.var)
  float rs  = rsqrtf(var + 1e-5f);
  float4 g4 = *(const float4*)(g + lane * 4);
  float4 b4 = *(const float4*)(be + lane * 4);
  float4 o;
  o.x = (v.x - mu) * rs * g4.x + b4.x;
  o.y = (v.y - mu) * rs * g4.y + b4.y;
  o.z = (v.z - mu) * rs * g4.z + b4.z;
  o.w = (v.w - mu) * rs * g4.w + b4.w;
  *(float4*)(outf + (size_t)row * 256 + lane * 4) = o;
  if constexpr (WBF) {
    uint2 p;
    p.x = (unsigned)f2bf(o.x) | ((unsigned)f2bf(o.y) << 16);
    p.y = (unsigned)f2bf(o.z) | ((unsigned)f2bf(o.w) << 16);
    *(uint2*)(outb + (size_t)row * 256 + lane * 4) = p;
  }
}

extern "C" void kernel_launch(void* const* d_in, const int* in_sizes, int n_in,
                              void* d_out, int out_size, void* d_ws, size_t ws_size,
                              hipStream_t stream)
{
  const float* src    = (const float*)d_in[0];
  const float* refpts = (const float*)d_in[2];
  const float* m0   = (const float*)d_in[4];
  const float* m1   = (const float*)d_in[5];
  const float* m2   = (const float*)d_in[6];
  const float* m3   = (const float*)d_in[7];
  const float* pm_w = (const float*)d_in[10];
  const float* pm_b = (const float*)d_in[11];
  const float* Wv   = (const float*)d_in[12];
  const float* bv   = (const float*)d_in[13];
  const float* Wo   = (const float*)d_in[14];
  const float* bo   = (const float*)d_in[15];
  const float* ln1g = (const float*)d_in[16];
  const float* ln1b = (const float*)d_in[17];
  const float* W1   = (const float*)d_in[18];
  const float* b1   = (const float*)d_in[19];
  const float* W2   = (const float*)d_in[20];
  const float* b2   = (const float*)d_in[21];
  const float* ln2g = (const float*)d_in[22];
  const float* ln2b = (const float*)d_in[23];
  float* out = (float*)d_out;
  char*  w   = (char*)d_ws;

  // workspace layout (bytes), ~67.2 MiB total:
  unsigned short* src_bf  = (unsigned short*)(w);               // 11,523,072
  float*          V       = (float*)(w + 11523072);             // 23,046,144
  unsigned short* attnpre = (unsigned short*)(w + 34569216);    // 11,523,072 (later x_bf)
  float*          offs    = (float*)(w + 46092288);             //  5,761,536
  float*          attw    = (float*)(w + 51853824);             //  2,880,768
  float*          xf32    = (float*)(w + 46092288);             // 23,046,144 (aliases offs+attw, dead by then)
  unsigned short* Wv_t    = (unsigned short*)(w + 69138432);    //    131,072
  unsigned short* Wo_t    = (unsigned short*)(w + 69269504);    //    131,072
  unsigned short* W1_t    = (unsigned short*)(w + 69400576);    //    524,288
  unsigned short* W2_t    = (unsigned short*)(w + 69924864);    //    524,288
  unsigned short* h1      = (unsigned short*)(w);               // 23,046,144 (aliases src_bf+V, dead)
  unsigned short* x_bf    = attnpre;

  // weight casts (Bt = N x K bf16)
  castT_kernel<<<dim3(256), 256, 0, stream>>>(Wv, Wv_t, 8, 8);
  castT_kernel<<<dim3(256), 256, 0, stream>>>(Wo, Wo_t, 8, 8);
  castT_kernel<<<dim3(1024), 256, 0, stream>>>(W1, W1_t, 8, 10);   // K=256,N=1024
  castT_kernel<<<dim3(1024), 256, 0, stream>>>(W2, W2_t, 10, 8);   // K=1024,N=256
  cast_src_kernel<<<dim3(5627), 256, 0, stream>>>(src, src_bf, TOK * 256 / 4);

  topk_kernel<<<dim3((TOK * NHEADS + 255) / 256), 256, 0, stream>>>(
      m0, m1, m2, m3, pm_w, pm_b, offs, attw);

  // V = src @ Wv + bv   (f32 out)
  mfma_gemm<0><<<dim3(176, 2), 256, 0, stream>>>(
      (const short*)src_bf, (const short*)Wv_t, bv, nullptr, V, nullptr,
      TOK, 256, 256);

  // deformable attention -> attnpre (bf16)
  sample_kernel<<<dim3((TOK + 3) / 4), 256, 0, stream>>>(
      V, refpts, offs, attw, attnpre);

  // y1 = attnpre @ Wo + bo + src  -> xf32
  mfma_gemm<2><<<dim3(176, 2), 256, 0, stream>>>(
      (const short*)attnpre, (const short*)Wo_t, bo, src, xf32, nullptr,
      TOK, 256, 256);

  // x = LN1(y1): xf32 in place + x_bf
  ln_kernel<true><<<dim3(5627), 256, 0, stream>>>(
      xf32, ln1g, ln1b, xf32, x_bf, TOK);

  // FFN, per batch chunk (h1 reuses dead src_bf+V region)
  for (int ch = 0; ch < 2; ++ch) {
    const unsigned short* xc = x_bf + (size_t)ch * LEN_T * 256;
    const float*          xr = xf32 + (size_t)ch * LEN_T * 256;
    float*                oc = out  + (size_t)ch * LEN_T * 256;
    mfma_gemm<1><<<dim3(88, 8), 256, 0, stream>>>(
        (const short*)xc, (const short*)W1_t, b1, nullptr, nullptr, h1,
        LEN_T, 1024, 256);
    mfma_gemm<2><<<dim3(88, 2), 256, 0, stream>>>(
        (const short*)h1, (const short*)W2_t, b2, xr, oc, nullptr,
        LEN_T, 256, 1024);
  }

  // out = LN2(out) in place
  ln_kernel<false><<<dim3(5627), 256, 0, stream>>>(
      out, ln2g, ln2b, out, nullptr, TOK);
}

// Round 3
// 372.187 us; speedup vs baseline: 2.1326x; 1.2116x over previous
//
#include <hip/hip_runtime.h>
#include <cstddef>
#include <cstdint>

#define LEN_T 11253
#define TOK   22506     // BS * LEN
#define NHEADS 8
#define DMODEL 256

typedef __attribute__((ext_vector_type(8))) short short8;   // bf16x8 (4 VGPR)
typedef __attribute__((ext_vector_type(4))) float f32x4;

__device__ __forceinline__ unsigned short f2bf(float f) {
  union { float f; unsigned u; } v; v.f = f;
  unsigned r = v.u + 0x7fffu + ((v.u >> 16) & 1u);   // RNE
  return (unsigned short)(r >> 16);
}
__device__ __forceinline__ float bfhi2f(unsigned u) {  // high 16 bits = bf16
  union { unsigned u; float f; } v; v.u = u & 0xffff0000u; return v.f;
}
__device__ __forceinline__ float bflo2f(unsigned u) {  // low 16 bits = bf16
  union { unsigned u; float f; } v; v.u = u << 16; return v.f;
}

__device__ __forceinline__ void gld_lds16(const void* g, void* l) {
  __builtin_amdgcn_global_load_lds(
      (const __attribute__((address_space(1))) void*)g,
      (__attribute__((address_space(3))) void*)l, 16, 0, 0);
}

// ---------------- cast src f32 -> bf16 ----------------
__global__ __launch_bounds__(256) void cast_src_kernel(
    const float* __restrict__ in, unsigned short* __restrict__ out, int n4)
{
  int i = blockIdx.x * 256 + threadIdx.x;
  if (i < n4) {
    float4 v = ((const float4*)in)[i];
    uint2 o;
    o.x = (unsigned)f2bf(v.x) | ((unsigned)f2bf(v.y) << 16);
    o.y = (unsigned)f2bf(v.z) | ((unsigned)f2bf(v.w) << 16);
    ((uint2*)out)[i] = o;
  }
}

// ------------- all 4 weight casts+transposes in ONE dispatch -------------
// blocks [0,256): Wv; [256,512): Wo; [512,1536): W1; [1536,2560): W2
__global__ __launch_bounds__(256) void castT_all_kernel(
    const float* __restrict__ Wv, const float* __restrict__ Wo,
    const float* __restrict__ W1, const float* __restrict__ W2,
    unsigned short* __restrict__ Wv_t, unsigned short* __restrict__ Wo_t,
    unsigned short* __restrict__ W1_t, unsigned short* __restrict__ W2_t)
{
  int blk = blockIdx.x;
  const float* W; unsigned short* Bt; int lk, ln, i;
  if (blk < 256)       { W = Wv; Bt = Wv_t; lk = 8;  ln = 8;  i = blk * 256 + threadIdx.x; }
  else if (blk < 512)  { W = Wo; Bt = Wo_t; lk = 8;  ln = 8;  i = (blk - 256) * 256 + threadIdx.x; }
  else if (blk < 1536) { W = W1; Bt = W1_t; lk = 8;  ln = 10; i = (blk - 512) * 256 + threadIdx.x; }
  else                 { W = W2; Bt = W2_t; lk = 10; ln = 8;  i = (blk - 1536) * 256 + threadIdx.x; }
  int n = i >> lk;
  int k = i & ((1 << lk) - 1);
  Bt[i] = f2bf(W[((size_t)k << ln) + n]);
}

// ---------------- top-k over 7x7 mask window ----------------
// offsets packed: byte p of offp[t] = j | (i<<4), j,i in [0,6]
__global__ __launch_bounds__(256) void topk_kernel(
    const float* __restrict__ m0, const float* __restrict__ m1,
    const float* __restrict__ m2, const float* __restrict__ m3,
    const float* __restrict__ pm_w, const float* __restrict__ pm_b,
    unsigned* __restrict__ offp, float* __restrict__ attw)
{
  int t = blockIdx.x * 256 + threadIdx.x;
  if (t >= TOK * NHEADS) return;
  int h  = t & 7;
  int bq = t >> 3;
  int b  = bq / LEN_T;
  int q  = bq - b * LEN_T;
  int l, st, H_, W_;
  const float* mk;
  if (q < 8464)       { l = 0; st = 0;     H_ = 92; W_ = 92; mk = m0; }
  else if (q < 10580) { l = 1; st = 8464;  H_ = 46; W_ = 46; mk = m1; }
  else if (q < 11109) { l = 2; st = 10580; H_ = 23; W_ = 23; mk = m2; }
  else                { l = 3; st = 11109; H_ = 12; W_ = 12; mk = m3; }
  int pos = q - st;
  int rr = pos / W_;
  int cc = pos - rr * W_;
  float w  = pm_w[l * NHEADS + h];
  float bb = pm_b[l * NHEADS + h];
  const float* mp = mk + (size_t)b * H_ * W_;

  float bestv[4] = {-1e30f, -1e30f, -1e30f, -1e30f};
  int   bestk[4] = {0, 0, 0, 0};
  for (int k = 0; k < 49; ++k) {
    int i = k / 7, j = k - (k / 7) * 7;
    int yy = rr + i - 3, xx = cc + j - 3;
    float v = 0.f;                       // zero padding outside the map
    if (yy >= 0 && yy < H_ && xx >= 0 && xx < W_) v = mp[yy * W_ + xx] * w + bb;
    if (v > bestv[3]) {                  // strict >: earlier k wins ties
      int p4 = 3;
      while (p4 > 0 && v > bestv[p4 - 1]) {
        bestv[p4] = bestv[p4 - 1]; bestk[p4] = bestk[p4 - 1]; --p4;
      }
      bestv[p4] = v; bestk[p4] = k;
    }
  }
  float mx = bestv[0];
  float ee[4];
  float s = 0.f;
  #pragma unroll
  for (int p = 0; p < 4; ++p) { ee[p] = __expf(bestv[p] - mx); s += ee[p]; }
  float inv = 1.f / (4.f * s);
  unsigned pk = 0;
  float* wp = attw + (size_t)t * 4;
  #pragma unroll
  for (int p = 0; p < 4; ++p) {
    int k = bestk[p];
    int i = k / 7, j = k - i * 7;
    pk |= (unsigned)(j | (i << 4)) << (8 * p);
    wp[p] = ee[p] * inv;
  }
  offp[t] = pk;
}

// ---------------- deformable bilinear sampling (bf16 V) ----------------
// one wave per token; XCD-contiguous token swizzle for L2 locality.
// grid MUST be 5627 blocks (= 8*703 + 3).
__global__ __launch_bounds__(256) void sample_kernel(
    const unsigned short* __restrict__ Vb, const float* __restrict__ refpts,
    const unsigned* __restrict__ offp, const float* __restrict__ attw,
    unsigned short* __restrict__ outp)
{
  __shared__ int4  sidx[4][128];
  __shared__ float4 swgt[4][128];
  const int wv   = threadIdx.x >> 6;
  const int lane = threadIdx.x & 63;
  // XCD swizzle: xcd = blk&7 gets contiguous chunk [xcd*703 + min(xcd,3), +len)
  const int bx = blockIdx.x & 7, by = blockIdx.x >> 3;
  const int nb = bx * 703 + min(bx, 3) + by;
  const int blk = nb * 4 + wv;             // b*LEN + q
  const bool ok = blk < TOK;

  if (ok) {
    const int b = (blk >= LEN_T) ? 1 : 0;
    const float* rp = refpts + (size_t)blk * 8;
    #pragma unroll
    for (int e = 0; e < 2; ++e) {
      int t = lane * 2 + e;                // t = lp*8 + h
      int h = t & 7, lp = t >> 3;
      int l = lp >> 2, p = lp & 3;
      unsigned pb = (offp[(size_t)blk * 8 + h] >> (8 * p)) & 0xffu;
      float ox = (float)(int)(pb & 15u) - 3.f;
      float oy = (float)(int)(pb >> 4)  - 3.f;
      float aw = attw[((size_t)blk * 8 + h) * 4 + p];
      int H_ = (l == 0) ? 92 : (l == 1) ? 46 : (l == 2) ? 23 : 12;  // square levels
      int st = (l == 0) ? 0  : (l == 1) ? 8464 : (l == 2) ? 10580 : 11109;
      float xx = rp[2 * l]     * (float)H_ - 0.5f + ox;
      float yy = rp[2 * l + 1] * (float)H_ - 0.5f + oy;
      float x0f = floorf(xx), y0f = floorf(yy);
      float tx = xx - x0f, ty = yy - y0f;
      int x0 = (int)x0f, y0 = (int)y0f;
      int base = b * LEN_T + st;
      float wc[4] = {(1.f - tx) * (1.f - ty), tx * (1.f - ty),
                     (1.f - tx) * ty,         tx * ty};
      int4 idx; float4 wg;
      int xs[4] = {x0, x0 + 1, x0, x0 + 1};
      int ys[4] = {y0, y0, y0 + 1, y0 + 1};
      int   id[4]; float wgt[4];
      #pragma unroll
      for (int c = 0; c < 4; ++c) {
        int xi = xs[c], yi = ys[c];
        bool v_ = (xi >= 0) & (xi < H_) & (yi >= 0) & (yi < H_);
        id[c]  = base + min(max(yi, 0), H_ - 1) * H_ + min(max(xi, 0), H_ - 1);
        wgt[c] = v_ ? aw * wc[c] : 0.f;
      }
      idx.x = id[0]; idx.y = id[1]; idx.z = id[2]; idx.w = id[3];
      wg.x = wgt[0]; wg.y = wgt[1]; wg.z = wgt[2]; wg.w = wgt[3];
      sidx[wv][t] = idx;
      swgt[wv][t] = wg;
    }
  }
  __syncthreads();

  if (ok) {
    const int h = lane >> 3, dg = lane & 7;
    const unsigned short* vb = Vb + h * 32 + dg * 4;   // 4 bf16 = 8B per lane
    f32x4 acc = {0.f, 0.f, 0.f, 0.f};
    #pragma unroll 4
    for (int lp = 0; lp < 16; ++lp) {
      int4  idx = sidx[wv][lp * 8 + h];
      float4 wg = swgt[wv][lp * 8 + h];
      uint2 u0 = *(const uint2*)(vb + (size_t)idx.x * DMODEL);
      uint2 u1 = *(const uint2*)(vb + (size_t)idx.y * DMODEL);
      uint2 u2 = *(const uint2*)(vb + (size_t)idx.z * DMODEL);
      uint2 u3 = *(const uint2*)(vb + (size_t)idx.w * DMODEL);
      acc.x += wg.x * bflo2f(u0.x) + wg.y * bflo2f(u1.x) + wg.z * bflo2f(u2.x) + wg.w * bflo2f(u3.x);
      acc.y += wg.x * bfhi2f(u0.x) + wg.y * bfhi2f(u1.x) + wg.z * bfhi2f(u2.x) + wg.w * bfhi2f(u3.x);
      acc.z += wg.x * bflo2f(u0.y) + wg.y * bflo2f(u1.y) + wg.z * bflo2f(u2.y) + wg.w * bflo2f(u3.y);
      acc.w += wg.x * bfhi2f(u0.y) + wg.y * bfhi2f(u1.y) + wg.z * bfhi2f(u2.y) + wg.w * bfhi2f(u3.y);
    }
    uint2 o;
    o.x = (unsigned)f2bf(acc.x) | ((unsigned)f2bf(acc.y) << 16);
    o.y = (unsigned)f2bf(acc.z) | ((unsigned)f2bf(acc.w) << 16);
    *(uint2*)(outp + (size_t)blk * DMODEL + h * 32 + dg * 4) = o;
  }
}

// ------------- bf16 MFMA GEMM, 64x256 tile, N=256, fused LN epilogue -------
// C[M,256] = A[M,K] @ Bt[256,K]^T + bias [...]
// 4 waves: wm=(w&1)*32, wn=(w>>1)*128; wave tile 32x128 (2x8 of 16x16x32).
// EPI 0: write bf16 Cb only.
// EPI 1: f = acc+bias+res; LN -> f32 C AND bf16 Cb.
// EPI 2: f = acc+bias+res; LN -> f32 C only.
template<int EPI>
__global__ __launch_bounds__(256) void gemm_n256(
    const short* __restrict__ A, const short* __restrict__ Bt,
    const float* __restrict__ bias, const float* __restrict__ res,
    const float* __restrict__ lng, const float* __restrict__ lnb,
    float* __restrict__ C, unsigned short* __restrict__ Cb,
    int M, int K)
{
  __shared__ short As[64 * 32]  __attribute__((aligned(16)));   //  4 KB
  __shared__ short Bs[256 * 32] __attribute__((aligned(16)));   // 16 KB
  __shared__ float2 lnred[64][2];                               //  1 KB
  const int tid  = threadIdx.x;
  const int w    = tid >> 6;
  const int lane = tid & 63;
  const int row0 = blockIdx.x * 64;

  f32x4 acc[2][8];
  #pragma unroll
  for (int i = 0; i < 2; ++i)
    #pragma unroll
    for (int j = 0; j < 8; ++j) acc[i][j] = (f32x4){0.f, 0.f, 0.f, 0.f};

  // staging: thread tid covers (row = tid>>2, k-quarter = tid&3), rows of 64B
  const int rA = min(row0 + (tid >> 2), M - 1);
  const short* ap = A + (size_t)rA * K + (tid & 3) * 8;
  short* lA = As + tid * 8;
  const short* bp[4]; short* lB[4];
  #pragma unroll
  for (int c = 0; c < 4; ++c) {
    int rB = c * 64 + (tid >> 2);
    bp[c] = Bt + (size_t)rB * K + (tid & 3) * 8;
    lB[c] = Bs + c * 2048 + tid * 8;
  }
  const int wm = (w & 1) * 32, wn = (w >> 1) * 128;
  const short* Abase = As + (size_t)(wm + (lane & 15)) * 32 + (lane >> 4) * 8;
  const short* Bbase = Bs + (size_t)(wn + (lane & 15)) * 32 + (lane >> 4) * 8;

  for (int kb = 0; kb < K; kb += 32) {
    gld_lds16(ap + kb, lA);
    #pragma unroll
    for (int c = 0; c < 4; ++c) gld_lds16(bp[c] + kb, lB[c]);
    __syncthreads();
    short8 af[2], bfr[8];
    #pragma unroll
    for (int mt = 0; mt < 2; ++mt) af[mt]  = *(const short8*)(Abase + mt * 16 * 32);
    #pragma unroll
    for (int nt = 0; nt < 8; ++nt) bfr[nt] = *(const short8*)(Bbase + nt * 16 * 32);
    #pragma unroll
    for (int mt = 0; mt < 2; ++mt)
      #pragma unroll
      for (int nt = 0; nt < 8; ++nt)
        acc[mt][nt] = __builtin_amdgcn_mfma_f32_16x16x32_bf16(
            af[mt], bfr[nt], acc[mt][nt], 0, 0, 0);
    __syncthreads();
  }

  // epilogue. C/D layout: col = lane&15 (+nt*16+wn), row = quad*4+r (+mt*16+wm)
  const int colq = lane & 15, quad = lane >> 4;
  float bia[8];
  #pragma unroll
  for (int nt = 0; nt < 8; ++nt) bia[nt] = bias[wn + nt * 16 + colq];

  if constexpr (EPI == 0) {
    #pragma unroll
    for (int mt = 0; mt < 2; ++mt)
      #pragma unroll
      for (int r = 0; r < 4; ++r) {
        int row = row0 + wm + mt * 16 + quad * 4 + r;
        if (row < M) {
          #pragma unroll
          for (int nt = 0; nt < 8; ++nt)
            Cb[(size_t)row * 256 + wn + nt * 16 + colq] =
                f2bf(acc[mt][nt][r] + bia[nt]);
        }
      }
  } else {
    // add bias + residual, accumulate row stats over this wave's 128 cols
    #pragma unroll
    for (int mt = 0; mt < 2; ++mt) {
      #pragma unroll
      for (int r = 0; r < 4; ++r) {
        int lrow = wm + mt * 16 + quad * 4 + r;
        int row  = row0 + lrow;
        int rowc = row < M ? row : M - 1;
        float s = 0.f, sq = 0.f;
        #pragma unroll
        for (int nt = 0; nt < 8; ++nt) {
          float f = acc[mt][nt][r] + bia[nt]
                  + res[(size_t)rowc * 256 + wn + nt * 16 + colq];
          acc[mt][nt][r] = f;
          s += f; sq += f * f;
        }
        #pragma unroll
        for (int off = 1; off < 16; off <<= 1) {
          s  += __shfl_xor(s,  off, 64);
          sq += __shfl_xor(sq, off, 64);
        }
        if (colq == 0) lnred[lrow][w >> 1] = (float2){s, sq};
      }
    }
    __syncthreads();
    #pragma unroll
    for (int mt = 0; mt < 2; ++mt) {
      #pragma unroll
      for (int r = 0; r < 4; ++r) {
        int lrow = wm + mt * 16 + quad * 4 + r;
        int row  = row0 + lrow;
        if (row >= M) continue;
        float2 p0 = lnred[lrow][0], p1 = lnred[lrow][1];
        float mu  = (p0.x + p1.x) * (1.f / 256.f);
        float var = (p0.y + p1.y) * (1.f / 256.f) - mu * mu;  // biased (jnp.var)
        float rs  = rsqrtf(var + 1e-5f);
        #pragma unroll
        for (int nt = 0; nt < 8; ++nt) {
          int col = wn + nt * 16 + colq;
          float o = (acc[mt][nt][r] - mu) * rs * lng[col] + lnb[col];
          C[(size_t)row * 256 + col] = o;
          if constexpr (EPI == 1)
            Cb[(size_t)row * 256 + col] = f2bf(o);
        }
      }
    }
  }
}

// ---------------- bf16 MFMA GEMM 128x128 (FFN1: relu -> bf16) ----------------
__global__ __launch_bounds__(256) void mfma_gemm_relu(
    const short* __restrict__ A, const short* __restrict__ Bt,
    const float* __restrict__ bias, unsigned short* __restrict__ Cb,
    int M, int N, int K)
{
  __shared__ short As[128 * 32] __attribute__((aligned(16)));
  __shared__ short Bs[128 * 32] __attribute__((aligned(16)));
  const int tid  = threadIdx.x;
  const int w    = tid >> 6;
  const int lane = tid & 63;
  const int row0 = blockIdx.x * 128;
  const int col0 = blockIdx.y * 128;

  f32x4 acc[4][4];
  #pragma unroll
  for (int i = 0; i < 4; ++i)
    #pragma unroll
    for (int j = 0; j < 4; ++j) acc[i][j] = (f32x4){0.f, 0.f, 0.f, 0.f};

  const int c0 = w * 2, c1 = w * 2 + 1;
  const int rA0 = min(row0 + c0 * 16 + (lane >> 2), M - 1);
  const int rA1 = min(row0 + c1 * 16 + (lane >> 2), M - 1);
  const int rB0 = col0 + c0 * 16 + (lane >> 2);
  const int rB1 = col0 + c1 * 16 + (lane >> 2);
  const short* a0p = A + (size_t)rA0 * K + (lane & 3) * 8;
  const short* a1p = A + (size_t)rA1 * K + (lane & 3) * 8;
  const short* b0p = Bt + (size_t)rB0 * K + (lane & 3) * 8;
  const short* b1p = Bt + (size_t)rB1 * K + (lane & 3) * 8;
  short* lA0 = As + c0 * 512 + lane * 8;
  short* lA1 = As + c1 * 512 + lane * 8;
  short* lB0 = Bs + c0 * 512 + lane * 8;
  short* lB1 = Bs + c1 * 512 + lane * 8;

  const int wm = (w & 1) * 64, wn = (w >> 1) * 64;
  const short* Abase = As + (size_t)(wm + (lane & 15)) * 32 + (lane >> 4) * 8;
  const short* Bbase = Bs + (size_t)(wn + (lane & 15)) * 32 + (lane >> 4) * 8;

  for (int kb = 0; kb < K; kb += 32) {
    gld_lds16(a0p + kb, lA0);
    gld_lds16(a1p + kb, lA1);
    gld_lds16(b0p + kb, lB0);
    gld_lds16(b1p + kb, lB1);
    __syncthreads();
    short8 af[4], bfr[4];
    #pragma unroll
    for (int mt = 0; mt < 4; ++mt) af[mt]  = *(const short8*)(Abase + mt * 16 * 32);
    #pragma unroll
    for (int nt = 0; nt < 4; ++nt) bfr[nt] = *(const short8*)(Bbase + nt * 16 * 32);
    #pragma unroll
    for (int mt = 0; mt < 4; ++mt)
      #pragma unroll
      for (int nt = 0; nt < 4; ++nt)
        acc[mt][nt] = __builtin_amdgcn_mfma_f32_16x16x32_bf16(
            af[mt], bfr[nt], acc[mt][nt], 0, 0, 0);
    __syncthreads();
  }

  const int colq = lane & 15, quad = lane >> 4;
  #pragma unroll
  for (int nt = 0; nt < 4; ++nt) {
    const int col = col0 + wn + nt * 16 + colq;
    const float bv_ = bias[col];
    #pragma unroll
    for (int mt = 0; mt < 4; ++mt) {
      #pragma unroll
      for (int r = 0; r < 4; ++r) {
        int row = row0 + wm + mt * 16 + quad * 4 + r;
        if (row < M)
          Cb[(size_t)row * N + col] = f2bf(fmaxf(acc[mt][nt][r] + bv_, 0.f));
      }
    }
  }
}

extern "C" void kernel_launch(void* const* d_in, const int* in_sizes, int n_in,
                              void* d_out, int out_size, void* d_ws, size_t ws_size,
                              hipStream_t stream)
{
  const float* src    = (const float*)d_in[0];
  const float* refpts = (const float*)d_in[2];
  const float* m0   = (const float*)d_in[4];
  const float* m1   = (const float*)d_in[5];
  const float* m2   = (const float*)d_in[6];
  const float* m3   = (const float*)d_in[7];
  const float* pm_w = (const float*)d_in[10];
  const float* pm_b = (const float*)d_in[11];
  const float* Wv   = (const float*)d_in[12];
  const float* bv   = (const float*)d_in[13];
  const float* Wo   = (const float*)d_in[14];
  const float* bo   = (const float*)d_in[15];
  const float* ln1g = (const float*)d_in[16];
  const float* ln1b = (const float*)d_in[17];
  const float* W1   = (const float*)d_in[18];
  const float* b1   = (const float*)d_in[19];
  const float* W2   = (const float*)d_in[20];
  const float* b2   = (const float*)d_in[21];
  const float* ln2g = (const float*)d_in[22];
  const float* ln2b = (const float*)d_in[23];
  float* out = (float*)d_out;
  char*  w   = (char*)d_ws;

  // workspace layout (bytes), ~59.6 MiB total:
  unsigned short* Vb      = (unsigned short*)(w);               // 11,523,072
  unsigned short* src_bf  = (unsigned short*)(w + 11523072);    // 11,523,072
  unsigned short* attnpre = (unsigned short*)(w + 23046144);    // 11,523,072 (later x_bf)
  float*          xf32    = (float*)(w + 34569216);             // 23,046,144
  float*          attw    = (float*)(w + 57615360);             //  2,880,768
  unsigned*       offp    = (unsigned*)(w + 60496128);          //    720,192
  unsigned short* Wv_t    = (unsigned short*)(w + 61216320);    //    131,072
  unsigned short* Wo_t    = (unsigned short*)(w + 61347392);    //    131,072
  unsigned short* W1_t    = (unsigned short*)(w + 61478464);    //    524,288
  unsigned short* W2_t    = (unsigned short*)(w + 62002752);    //    524,288
  unsigned short* h1      = (unsigned short*)(w);               // 23,046,144 (aliases Vb+src_bf, dead by FFN)
  unsigned short* x_bf    = attnpre;

  castT_all_kernel<<<dim3(2560), 256, 0, stream>>>(
      Wv, Wo, W1, W2, Wv_t, Wo_t, W1_t, W2_t);
  cast_src_kernel<<<dim3(5627), 256, 0, stream>>>(src, src_bf, TOK * 256 / 4);
  topk_kernel<<<dim3((TOK * NHEADS + 255) / 256), 256, 0, stream>>>(
      m0, m1, m2, m3, pm_w, pm_b, offp, attw);

  // V = src @ Wv + bv  -> bf16 Vb
  gemm_n256<0><<<dim3(352), 256, 0, stream>>>(
      (const short*)src_bf, (const short*)Wv_t, bv, nullptr, nullptr, nullptr,
      nullptr, Vb, TOK, 256);

  // deformable attention -> attnpre (bf16)
  sample_kernel<<<dim3(5627), 256, 0, stream>>>(
      Vb, refpts, offp, attw, attnpre);

  // x = LN1(attnpre @ Wo + bo + src) -> xf32 + x_bf
  gemm_n256<1><<<dim3(352), 256, 0, stream>>>(
      (const short*)attnpre, (const short*)Wo_t, bo, src, ln1g, ln1b,
      xf32, x_bf, TOK, 256);

  // FFN per batch chunk; out = LN2(x + relu(x@W1+b1)@W2 + b2) fused
  for (int ch = 0; ch < 2; ++ch) {
    const unsigned short* xc = x_bf + (size_t)ch * LEN_T * 256;
    const float*          xr = xf32 + (size_t)ch * LEN_T * 256;
    float*                oc = out  + (size_t)ch * LEN_T * 256;
    mfma_gemm_relu<<<dim3(88, 8), 256, 0, stream>>>(
        (const short*)xc, (const short*)W1_t, b1, h1, LEN_T, 1024, 256);
    gemm_n256<2><<<dim3(176), 256, 0, stream>>>(
        (const short*)h1, (const short*)W2_t, b2, xr, ln2g, ln2b,
        oc, nullptr, LEN_T, 1024);
  }
}

// Round 4
// 338.648 us; speedup vs baseline: 2.3438x; 1.0990x over previous
//
#include <hip/hip_runtime.h>
#include <cstddef>
#include <cstdint>

#define LEN_T 11253
#define TOK   22506     // BS * LEN
#define NHEADS 8
#define DMODEL 256

typedef __attribute__((ext_vector_type(8))) short short8;   // bf16x8 (4 VGPR)
typedef __attribute__((ext_vector_type(4))) float f32x4;

__device__ __forceinline__ unsigned short f2bf(float f) {
  union { float f; unsigned u; } v; v.f = f;
  unsigned r = v.u + 0x7fffu + ((v.u >> 16) & 1u);   // RNE
  return (unsigned short)(r >> 16);
}
__device__ __forceinline__ float bfhi2f(unsigned u) {  // high 16 bits = bf16
  union { unsigned u; float f; } v; v.u = u & 0xffff0000u; return v.f;
}
__device__ __forceinline__ float bflo2f(unsigned u) {  // low 16 bits = bf16
  union { unsigned u; float f; } v; v.u = u << 16; return v.f;
}

__device__ __forceinline__ void gld_lds16(const void* g, void* l) {
  __builtin_amdgcn_global_load_lds(
      (const __attribute__((address_space(1))) void*)g,
      (__attribute__((address_space(3))) void*)l, 16, 0, 0);
}

// ============ pre-kernel: weight cast/transpose + top-k, ONE dispatch =======
// blocks [0,704): topk; [704,960): Wv; [960,1216): Wo; [1216,2240): W1;
// [2240,3264): W2
__global__ __launch_bounds__(256) void pre_kernel(
    const float* __restrict__ m0, const float* __restrict__ m1,
    const float* __restrict__ m2, const float* __restrict__ m3,
    const float* __restrict__ pm_w, const float* __restrict__ pm_b,
    const float* __restrict__ Wv, const float* __restrict__ Wo,
    const float* __restrict__ W1, const float* __restrict__ W2,
    unsigned short* __restrict__ Wv_t, unsigned short* __restrict__ Wo_t,
    unsigned short* __restrict__ W1_t, unsigned short* __restrict__ W2_t,
    unsigned* __restrict__ offp, float* __restrict__ attw)
{
  int blk = blockIdx.x;
  if (blk >= 704) {   // ---- weight cast+transpose: Bt[n][k] = bf16(W[k][n])
    int cb = blk - 704;
    const float* W; unsigned short* Bt; int lk, ln, i;
    if (cb < 256)       { W = Wv; Bt = Wv_t; lk = 8;  ln = 8;  i = cb * 256 + threadIdx.x; }
    else if (cb < 512)  { W = Wo; Bt = Wo_t; lk = 8;  ln = 8;  i = (cb - 256) * 256 + threadIdx.x; }
    else if (cb < 1536) { W = W1; Bt = W1_t; lk = 8;  ln = 10; i = (cb - 512) * 256 + threadIdx.x; }
    else                { W = W2; Bt = W2_t; lk = 10; ln = 8;  i = (cb - 1536) * 256 + threadIdx.x; }
    int n = i >> lk;
    int k = i & ((1 << lk) - 1);
    Bt[i] = f2bf(W[((size_t)k << ln) + n]);
    return;
  }
  // ---- top-k over 7x7 window; offp byte p = j | (i<<4)
  int t = blk * 256 + threadIdx.x;
  if (t >= TOK * NHEADS) return;
  int h  = t & 7;
  int bq = t >> 3;
  int b  = bq / LEN_T;
  int q  = bq - b * LEN_T;
  int l, H_, W_;
  const float* mk;
  if (q < 8464)       { l = 0; H_ = 92; W_ = 92; mk = m0; }
  else if (q < 10580) { l = 1; H_ = 46; W_ = 46; mk = m1; }
  else if (q < 11109) { l = 2; H_ = 23; W_ = 23; mk = m2; }
  else                { l = 3; H_ = 12; W_ = 12; mk = m3; }
  int st = (l == 0) ? 0 : (l == 1) ? 8464 : (l == 2) ? 10580 : 11109;
  int pos = q - st;
  int rr = pos / W_;
  int cc = pos - rr * W_;
  float w  = pm_w[l * NHEADS + h];
  float bb = pm_b[l * NHEADS + h];
  const float* mp = mk + (size_t)b * H_ * W_;

  float bestv[4] = {-1e30f, -1e30f, -1e30f, -1e30f};
  int   bestk[4] = {0, 0, 0, 0};
  for (int k = 0; k < 49; ++k) {
    int i = k / 7, j = k - (k / 7) * 7;
    int yy = rr + i - 3, xx = cc + j - 3;
    float v = 0.f;                       // zero padding outside the map
    if (yy >= 0 && yy < H_ && xx >= 0 && xx < W_) v = mp[yy * W_ + xx] * w + bb;
    if (v > bestv[3]) {                  // strict >: earlier k wins ties
      int p4 = 3;
      while (p4 > 0 && v > bestv[p4 - 1]) {
        bestv[p4] = bestv[p4 - 1]; bestk[p4] = bestk[p4 - 1]; --p4;
      }
      bestv[p4] = v; bestk[p4] = k;
    }
  }
  float mx = bestv[0];
  float ee[4];
  float s = 0.f;
  #pragma unroll
  for (int p = 0; p < 4; ++p) { ee[p] = __expf(bestv[p] - mx); s += ee[p]; }
  float inv = 1.f / (4.f * s);
  unsigned pk = 0;
  float* wp = attw + (size_t)t * 4;
  #pragma unroll
  for (int p = 0; p < 4; ++p) {
    int k = bestk[p];
    int i = k / 7, j = k - i * 7;
    pk |= (unsigned)(j | (i << 4)) << (8 * p);
    wp[p] = ee[p] * inv;
  }
  offp[t] = pk;
}

// ---------------- deformable bilinear sampling (bf16 V) ----------------
// one wave per token; XCD-contiguous token swizzle for L2 locality.
// grid MUST be 5627 blocks (= 8*703 + 3).
__global__ __launch_bounds__(256) void sample_kernel(
    const unsigned short* __restrict__ Vb, const float* __restrict__ refpts,
    const unsigned* __restrict__ offp, const float* __restrict__ attw,
    unsigned short* __restrict__ outp)
{
  __shared__ int4  sidx[4][128];
  __shared__ float4 swgt[4][128];
  const int wv   = threadIdx.x >> 6;
  const int lane = threadIdx.x & 63;
  const int bx = blockIdx.x & 7, by = blockIdx.x >> 3;
  const int nb = bx * 703 + min(bx, 3) + by;
  const int blk = nb * 4 + wv;             // b*LEN + q
  const bool ok = blk < TOK;

  if (ok) {
    const int b = (blk >= LEN_T) ? 1 : 0;
    const float* rp = refpts + (size_t)blk * 8;
    #pragma unroll
    for (int e = 0; e < 2; ++e) {
      int t = lane * 2 + e;                // t = lp*8 + h
      int h = t & 7, lp = t >> 3;
      int l = lp >> 2, p = lp & 3;
      unsigned pb = (offp[(size_t)blk * 8 + h] >> (8 * p)) & 0xffu;
      float ox = (float)(int)(pb & 15u) - 3.f;
      float oy = (float)(int)(pb >> 4)  - 3.f;
      float aw = attw[((size_t)blk * 8 + h) * 4 + p];
      int H_ = (l == 0) ? 92 : (l == 1) ? 46 : (l == 2) ? 23 : 12;  // square levels
      int st = (l == 0) ? 0  : (l == 1) ? 8464 : (l == 2) ? 10580 : 11109;
      float xx = rp[2 * l]     * (float)H_ - 0.5f + ox;
      float yy = rp[2 * l + 1] * (float)H_ - 0.5f + oy;
      float x0f = floorf(xx), y0f = floorf(yy);
      float tx = xx - x0f, ty = yy - y0f;
      int x0 = (int)x0f, y0 = (int)y0f;
      int base = b * LEN_T + st;
      float wc[4] = {(1.f - tx) * (1.f - ty), tx * (1.f - ty),
                     (1.f - tx) * ty,         tx * ty};
      int4 idx; float4 wg;
      int xs[4] = {x0, x0 + 1, x0, x0 + 1};
      int ys[4] = {y0, y0, y0 + 1, y0 + 1};
      int   id[4]; float wgt[4];
      #pragma unroll
      for (int c = 0; c < 4; ++c) {
        int xi = xs[c], yi = ys[c];
        bool v_ = (xi >= 0) & (xi < H_) & (yi >= 0) & (yi < H_);
        id[c]  = base + min(max(yi, 0), H_ - 1) * H_ + min(max(xi, 0), H_ - 1);
        wgt[c] = v_ ? aw * wc[c] : 0.f;
      }
      idx.x = id[0]; idx.y = id[1]; idx.z = id[2]; idx.w = id[3];
      wg.x = wgt[0]; wg.y = wgt[1]; wg.z = wgt[2]; wg.w = wgt[3];
      sidx[wv][t] = idx;
      swgt[wv][t] = wg;
    }
  }
  __syncthreads();

  if (ok) {
    const int h = lane >> 3, dg = lane & 7;
    const unsigned short* vb = Vb + h * 32 + dg * 4;   // 4 bf16 = 8B per lane
    f32x4 acc = {0.f, 0.f, 0.f, 0.f};
    #pragma unroll 4
    for (int lp = 0; lp < 16; ++lp) {
      int4  idx = sidx[wv][lp * 8 + h];
      float4 wg = swgt[wv][lp * 8 + h];
      uint2 u0 = *(const uint2*)(vb + (size_t)idx.x * DMODEL);
      uint2 u1 = *(const uint2*)(vb + (size_t)idx.y * DMODEL);
      uint2 u2 = *(const uint2*)(vb + (size_t)idx.z * DMODEL);
      uint2 u3 = *(const uint2*)(vb + (size_t)idx.w * DMODEL);
      acc.x += wg.x * bflo2f(u0.x) + wg.y * bflo2f(u1.x) + wg.z * bflo2f(u2.x) + wg.w * bflo2f(u3.x);
      acc.y += wg.x * bfhi2f(u0.x) + wg.y * bfhi2f(u1.x) + wg.z * bfhi2f(u2.x) + wg.w * bfhi2f(u3.x);
      acc.z += wg.x * bflo2f(u0.y) + wg.y * bflo2f(u1.y) + wg.z * bflo2f(u2.y) + wg.w * bflo2f(u3.y);
      acc.w += wg.x * bfhi2f(u0.y) + wg.y * bfhi2f(u1.y) + wg.z * bfhi2f(u2.y) + wg.w * bfhi2f(u3.y);
    }
    uint2 o;
    o.x = (unsigned)f2bf(acc.x) | ((unsigned)f2bf(acc.y) << 16);
    o.y = (unsigned)f2bf(acc.z) | ((unsigned)f2bf(acc.w) << 16);
    *(uint2*)(outp + (size_t)blk * DMODEL + h * 32 + dg * 4) = o;
  }
}

// ============ weight-resident K=256 MFMA GEMM ==============================
// C[M,N] = A[M,256] @ Bt[N,256]^T (+bias...). B fragments live in VGPRs for
// the whole kernel (8 k-chunks x 4 n-tiles x short8 = 128 VGPRs/lane); only A
// goes through LDS (double-buffered 2x4KB). Block = 64 rows x 256 cols,
// 4 waves, wave tile 64x64 (4x4 of 16x16x32 MFMA).
// EPI 0: Cb = bf16(acc + bias)
// EPI 1: LN(acc + bias + res) -> C f32 AND Cb bf16   (N must be 256)
// EPI 2: Cb = bf16(relu(acc + bias))
// AF32: A is f32, cast to bf16 inline during staging.
template<int EPI, bool AF32>
__global__ __launch_bounds__(256, 2) void gemm_k256(
    const void* __restrict__ Aptr, const short* __restrict__ Bt,
    const float* __restrict__ bias, const float* __restrict__ res,
    const float* __restrict__ lng, const float* __restrict__ lnb,
    float* __restrict__ C, unsigned short* __restrict__ Cb,
    int M, int N)
{
  __shared__ short As[2][64 * 32] __attribute__((aligned(16)));  // 2 x 4 KB
  __shared__ float2 lnred[64][4];
  const int tid  = threadIdx.x;
  const int w    = tid >> 6;
  const int lane = tid & 63;
  const int row0 = blockIdx.x * 64;
  const int wn   = blockIdx.y * 256 + w * 64;   // this wave's 64 output cols
  const int colq = lane & 15, quad = lane >> 4;
  const int kq8  = quad * 8;

  // ---- B fragments: direct global -> VGPR, fragment layout, resident ----
  short8 bq[8][4];
  #pragma unroll
  for (int kc = 0; kc < 8; ++kc)
    #pragma unroll
    for (int nt = 0; nt < 4; ++nt)
      bq[kc][nt] = *(const short8*)(Bt + (size_t)(wn + nt * 16 + colq) * 256
                                       + kc * 32 + kq8);

  f32x4 acc[4][4];
  #pragma unroll
  for (int i = 0; i < 4; ++i)
    #pragma unroll
    for (int j = 0; j < 4; ++j) acc[i][j] = (f32x4){0.f, 0.f, 0.f, 0.f};

  // ---- A staging: thread covers (row = tid>>2, k-quarter = tid&3), 16B ----
  const int rA  = min(row0 + (tid >> 2), M - 1);
  const int kq4 = (tid & 3) * 8;
  const float* Af = (const float*)Aptr;
  const short* Ab = (const short*)Aptr;

  auto stageA = [&](int kb, int nbuf) {
    if constexpr (AF32) {
      const float* ap = Af + (size_t)rA * 256 + kb * 32 + kq4;
      float4 f0 = *(const float4*)ap;
      float4 f1 = *(const float4*)(ap + 4);
      uint4 u;
      u.x = (unsigned)f2bf(f0.x) | ((unsigned)f2bf(f0.y) << 16);
      u.y = (unsigned)f2bf(f0.z) | ((unsigned)f2bf(f0.w) << 16);
      u.z = (unsigned)f2bf(f1.x) | ((unsigned)f2bf(f1.y) << 16);
      u.w = (unsigned)f2bf(f1.z) | ((unsigned)f2bf(f1.w) << 16);
      *(uint4*)(As[nbuf] + (size_t)tid * 8) = u;
    } else {
      gld_lds16(Ab + (size_t)rA * 256 + kb * 32 + kq4, As[nbuf] + (size_t)tid * 8);
    }
  };

  stageA(0, 0);
  __syncthreads();
  int buf = 0;
  #pragma unroll
  for (int kb = 0; kb < 8; ++kb) {
    if (kb < 7) stageA(kb + 1, buf ^ 1);
    short8 af[4];
    #pragma unroll
    for (int mt = 0; mt < 4; ++mt)
      af[mt] = *(const short8*)(As[buf] + (size_t)(mt * 16 + colq) * 32 + kq8);
    #pragma unroll
    for (int mt = 0; mt < 4; ++mt)
      #pragma unroll
      for (int nt = 0; nt < 4; ++nt)
        acc[mt][nt] = __builtin_amdgcn_mfma_f32_16x16x32_bf16(
            af[mt], bq[kb][nt], acc[mt][nt], 0, 0, 0);
    __syncthreads();
    buf ^= 1;
  }

  // ---- epilogue: C/D layout col = lane&15, row = quad*4 + reg ----
  float bia[4];
  #pragma unroll
  for (int nt = 0; nt < 4; ++nt) bia[nt] = bias[wn + nt * 16 + colq];

  if constexpr (EPI == 1) {
    #pragma unroll
    for (int mt = 0; mt < 4; ++mt) {
      #pragma unroll
      for (int r = 0; r < 4; ++r) {
        int lrow = mt * 16 + quad * 4 + r;
        int rowc = min(row0 + lrow, M - 1);
        float s = 0.f, sq = 0.f;
        #pragma unroll
        for (int nt = 0; nt < 4; ++nt) {
          float f = acc[mt][nt][r] + bia[nt]
                  + res[(size_t)rowc * 256 + wn + nt * 16 + colq];
          acc[mt][nt][r] = f;
          s += f; sq += f * f;
        }
        #pragma unroll
        for (int off = 1; off < 16; off <<= 1) {
          s  += __shfl_xor(s,  off, 64);
          sq += __shfl_xor(sq, off, 64);
        }
        if (colq == 0) lnred[lrow][w] = (float2){s, sq};
      }
    }
    __syncthreads();
    #pragma unroll
    for (int mt = 0; mt < 4; ++mt) {
      #pragma unroll
      for (int r = 0; r < 4; ++r) {
        int lrow = mt * 16 + quad * 4 + r;
        int row  = row0 + lrow;
        if (row >= M) continue;
        float2 p0 = lnred[lrow][0], p1 = lnred[lrow][1];
        float2 p2 = lnred[lrow][2], p3 = lnred[lrow][3];
        float mu  = (p0.x + p1.x + p2.x + p3.x) * (1.f / 256.f);
        float var = (p0.y + p1.y + p2.y + p3.y) * (1.f / 256.f) - mu * mu;
        float rs  = rsqrtf(var + 1e-5f);          // biased var (jnp.var)
        #pragma unroll
        for (int nt = 0; nt < 4; ++nt) {
          int col = wn + nt * 16 + colq;
          float o = (acc[mt][nt][r] - mu) * rs * lng[col] + lnb[col];
          C[(size_t)row * 256 + col]  = o;
          Cb[(size_t)row * 256 + col] = f2bf(o);
        }
      }
    }
  } else {
    #pragma unroll
    for (int mt = 0; mt < 4; ++mt) {
      #pragma unroll
      for (int r = 0; r < 4; ++r) {
        int row = row0 + mt * 16 + quad * 4 + r;
        if (row < M) {
          #pragma unroll
          for (int nt = 0; nt < 4; ++nt) {
            float f = acc[mt][nt][r] + bia[nt];
            if constexpr (EPI == 2) f = fmaxf(f, 0.f);
            Cb[(size_t)row * N + wn + nt * 16 + colq] = f2bf(f);
          }
        }
      }
    }
  }
}

// ------------- bf16 MFMA GEMM, 64x256 tile (FFN2, K=1024) -------------
// out = LN2(A @ Bt^T + bias + res); LDS-staged A and B, BK=32.
__global__ __launch_bounds__(256) void gemm_n256_ln(
    const short* __restrict__ A, const short* __restrict__ Bt,
    const float* __restrict__ bias, const float* __restrict__ res,
    const float* __restrict__ lng, const float* __restrict__ lnb,
    float* __restrict__ C, int M, int K)
{
  __shared__ short As[64 * 32]  __attribute__((aligned(16)));   //  4 KB
  __shared__ short Bs[256 * 32] __attribute__((aligned(16)));   // 16 KB
  __shared__ float2 lnred[64][2];                               //  1 KB
  const int tid  = threadIdx.x;
  const int w    = tid >> 6;
  const int lane = tid & 63;
  const int row0 = blockIdx.x * 64;

  f32x4 acc[2][8];
  #pragma unroll
  for (int i = 0; i < 2; ++i)
    #pragma unroll
    for (int j = 0; j < 8; ++j) acc[i][j] = (f32x4){0.f, 0.f, 0.f, 0.f};

  const int rA = min(row0 + (tid >> 2), M - 1);
  const short* ap = A + (size_t)rA * K + (tid & 3) * 8;
  short* lA = As + tid * 8;
  const short* bp[4]; short* lB[4];
  #pragma unroll
  for (int c = 0; c < 4; ++c) {
    int rB = c * 64 + (tid >> 2);
    bp[c] = Bt + (size_t)rB * K + (tid & 3) * 8;
    lB[c] = Bs + c * 2048 + tid * 8;
  }
  const int wm = (w & 1) * 32, wn = (w >> 1) * 128;
  const short* Abase = As + (size_t)(wm + (lane & 15)) * 32 + (lane >> 4) * 8;
  const short* Bbase = Bs + (size_t)(wn + (lane & 15)) * 32 + (lane >> 4) * 8;

  for (int kb = 0; kb < K; kb += 32) {
    gld_lds16(ap + kb, lA);
    #pragma unroll
    for (int c = 0; c < 4; ++c) gld_lds16(bp[c] + kb, lB[c]);
    __syncthreads();
    short8 af[2], bfr[8];
    #pragma unroll
    for (int mt = 0; mt < 2; ++mt) af[mt]  = *(const short8*)(Abase + mt * 16 * 32);
    #pragma unroll
    for (int nt = 0; nt < 8; ++nt) bfr[nt] = *(const short8*)(Bbase + nt * 16 * 32);
    #pragma unroll
    for (int mt = 0; mt < 2; ++mt)
      #pragma unroll
      for (int nt = 0; nt < 8; ++nt)
        acc[mt][nt] = __builtin_amdgcn_mfma_f32_16x16x32_bf16(
            af[mt], bfr[nt], acc[mt][nt], 0, 0, 0);
    __syncthreads();
  }

  const int colq = lane & 15, quad = lane >> 4;
  float bia[8];
  #pragma unroll
  for (int nt = 0; nt < 8; ++nt) bia[nt] = bias[wn + nt * 16 + colq];

  #pragma unroll
  for (int mt = 0; mt < 2; ++mt) {
    #pragma unroll
    for (int r = 0; r < 4; ++r) {
      int lrow = wm + mt * 16 + quad * 4 + r;
      int rowc = min(row0 + lrow, M - 1);
      float s = 0.f, sq = 0.f;
      #pragma unroll
      for (int nt = 0; nt < 8; ++nt) {
        float f = acc[mt][nt][r] + bia[nt]
                + res[(size_t)rowc * 256 + wn + nt * 16 + colq];
        acc[mt][nt][r] = f;
        s += f; sq += f * f;
      }
      #pragma unroll
      for (int off = 1; off < 16; off <<= 1) {
        s  += __shfl_xor(s,  off, 64);
        sq += __shfl_xor(sq, off, 64);
      }
      if (colq == 0) lnred[lrow][w >> 1] = (float2){s, sq};
    }
  }
  __syncthreads();
  #pragma unroll
  for (int mt = 0; mt < 2; ++mt) {
    #pragma unroll
    for (int r = 0; r < 4; ++r) {
      int lrow = wm + mt * 16 + quad * 4 + r;
      int row  = row0 + lrow;
      if (row >= M) continue;
      float2 p0 = lnred[lrow][0], p1 = lnred[lrow][1];
      float mu  = (p0.x + p1.x) * (1.f / 256.f);
      float var = (p0.y + p1.y) * (1.f / 256.f) - mu * mu;  // biased (jnp.var)
      float rs  = rsqrtf(var + 1e-5f);
      #pragma unroll
      for (int nt = 0; nt < 8; ++nt) {
        int col = wn + nt * 16 + colq;
        C[(size_t)row * 256 + col] =
            (acc[mt][nt][r] - mu) * rs * lng[col] + lnb[col];
      }
    }
  }
}

extern "C" void kernel_launch(void* const* d_in, const int* in_sizes, int n_in,
                              void* d_out, int out_size, void* d_ws, size_t ws_size,
                              hipStream_t stream)
{
  const float* src    = (const float*)d_in[0];
  const float* refpts = (const float*)d_in[2];
  const float* m0   = (const float*)d_in[4];
  const float* m1   = (const float*)d_in[5];
  const float* m2   = (const float*)d_in[6];
  const float* m3   = (const float*)d_in[7];
  const float* pm_w = (const float*)d_in[10];
  const float* pm_b = (const float*)d_in[11];
  const float* Wv   = (const float*)d_in[12];
  const float* bv   = (const float*)d_in[13];
  const float* Wo   = (const float*)d_in[14];
  const float* bo   = (const float*)d_in[15];
  const float* W1   = (const float*)d_in[18];
  const float* b1   = (const float*)d_in[19];
  const float* W2   = (const float*)d_in[20];
  const float* b2   = (const float*)d_in[21];
  const float* ln1g = (const float*)d_in[16];
  const float* ln1b = (const float*)d_in[17];
  const float* ln2g = (const float*)d_in[22];
  const float* ln2b = (const float*)d_in[23];
  float* out = (float*)d_out;
  char*  w   = (char*)d_ws;

  // big path needs full-batch h1 (46 MB): total 97,096,256 B.
  // chunked path: h1 halved, total ~74 MB (known-safe).
  const bool big = ws_size >= 97096256ull;
  const size_t H1SZ = big ? 46092288ull : 23046144ull;

  unsigned short* Vb      = (unsigned short*)(w);                // 11,523,072
  unsigned short* attnpre = (unsigned short*)(w + 11523072);     // 11,523,072 (= x_bf)
  float*          xf32    = (float*)(w + 23046144);              // 23,046,144
  unsigned short* h1      = (unsigned short*)(w + 46092288);     // H1SZ
  char*           tail    = w + 46092288 + H1SZ;
  float*          attw    = (float*)(tail);                      //  2,880,768
  unsigned*       offp    = (unsigned*)(tail + 2880768);         //    720,192
  unsigned short* Wv_t    = (unsigned short*)(tail + 3600960);   //    131,072
  unsigned short* Wo_t    = (unsigned short*)(tail + 3732032);   //    131,072
  unsigned short* W1_t    = (unsigned short*)(tail + 3863104);   //    524,288
  unsigned short* W2_t    = (unsigned short*)(tail + 4387392);   //    524,288
  unsigned short* x_bf    = attnpre;

  pre_kernel<<<dim3(3264), 256, 0, stream>>>(
      m0, m1, m2, m3, pm_w, pm_b, Wv, Wo, W1, W2,
      Wv_t, Wo_t, W1_t, W2_t, offp, attw);

  // V = bf16(src @ Wv + bv), inline f32->bf16 A cast
  gemm_k256<0, true><<<dim3(352, 1), 256, 0, stream>>>(
      src, (const short*)Wv_t, bv, nullptr, nullptr, nullptr,
      nullptr, Vb, TOK, 256);

  // deformable attention -> attnpre (bf16)
  sample_kernel<<<dim3(5627), 256, 0, stream>>>(
      Vb, refpts, offp, attw, attnpre);

  // x = LN1(attnpre @ Wo + bo + src) -> xf32 (f32) + x_bf (bf16, in place)
  gemm_k256<1, false><<<dim3(352, 1), 256, 0, stream>>>(
      attnpre, (const short*)Wo_t, bo, src, ln1g, ln1b,
      xf32, x_bf, TOK, 256);

  if (big) {
    gemm_k256<2, false><<<dim3(352, 4), 256, 0, stream>>>(
        x_bf, (const short*)W1_t, b1, nullptr, nullptr, nullptr,
        nullptr, h1, TOK, 1024);
    gemm_n256_ln<<<dim3(352), 256, 0, stream>>>(
        (const short*)h1, (const short*)W2_t, b2, xf32, ln2g, ln2b,
        out, TOK, 1024);
  } else {
    for (int ch = 0; ch < 2; ++ch) {
      const unsigned short* xc = x_bf + (size_t)ch * LEN_T * 256;
      const float*          xr = xf32 + (size_t)ch * LEN_T * 256;
      float*                oc = out  + (size_t)ch * LEN_T * 256;
      gemm_k256<2, false><<<dim3(176, 4), 256, 0, stream>>>(
          xc, (const short*)W1_t, b1, nullptr, nullptr, nullptr,
          nullptr, h1, LEN_T, 1024);
      gemm_n256_ln<<<dim3(176), 256, 0, stream>>>(
          (const short*)h1, (const short*)W2_t, b2, xr, ln2g, ln2b,
          oc, LEN_T, 1024);
    }
  }
}